// Round 3
// baseline (426.178 us; speedup 1.0000x reference)
//
#include <hip/hip_runtime.h>

// MHA forward: D_MODEL=1024, H=16, DEPTH=64, B=2, S=2048, M=B*S=4096
// bf16 MFMA (16x16x32) everywhere, fp32 accumulation.
// Round 2: fix bf16x8<-u16x8 bit-cast compile error in attn Q load.

typedef float f32x4 __attribute__((ext_vector_type(4)));
typedef __bf16 bf16x8 __attribute__((ext_vector_type(8)));
typedef unsigned short u16x8 __attribute__((ext_vector_type(8)));

#define DEV static __device__ __forceinline__

DEV unsigned short f2bf(float x) {
  return __builtin_bit_cast(unsigned short, static_cast<__bf16>(x));
}
DEV bf16x8 ld8(const unsigned short* p) {
  return __builtin_bit_cast(bf16x8, *reinterpret_cast<const u16x8*>(p));
}
DEV f32x4 mfma16(bf16x8 a, bf16x8 b, f32x4 c) {
  return __builtin_amdgcn_mfma_f32_16x16x32_bf16(a, b, c, 0, 0, 0);
}

// ---------------------------------------------------------------------------
// GEMM: C[m][n] = sum_k A[m][k] * W[n][k]  (+bias[n]) * scale
// A: 4096x1024 (fp32 or bf16-bits), W: 1024x1024 fp32 (row n = output feature)
// Tile: BM=128, BN=64, BK=64. 256 threads = 4 waves (2x2), wave tile 64x32.
// MODE 0: out bf16, head-split  [B,H,S,64]
// MODE 1: out bf16, head-split transposed [B,H,64,S]
// MODE 2: out fp32, plain [M,1024]
// ---------------------------------------------------------------------------
template<bool AF32, int MODE>
__global__ __launch_bounds__(256)
void gemm_proj(const void* __restrict__ Ag, const float* __restrict__ Wg,
               const float* __restrict__ bias, void* __restrict__ outg,
               float scale)
{
  __shared__ unsigned short lA[128][72];
  __shared__ unsigned short lB[64][72];
  const int tid = threadIdx.x;
  const int lane = tid & 63, wid = tid >> 6;
  const int lr = lane & 15, lg = lane >> 4;
  const int wr = wid >> 1, wc = wid & 1;
  const int mbase = blockIdx.y * 128;
  const int nbase = blockIdx.x * 64;

  const f32x4 zf = {0.f, 0.f, 0.f, 0.f};
  f32x4 acc[4][2];
#pragma unroll
  for (int i = 0; i < 4; ++i)
#pragma unroll
    for (int j = 0; j < 2; ++j) acc[i][j] = zf;

  for (int kt = 0; kt < 16; ++kt) {
    const int k0 = kt * 64;
    // stage A tile (128 x 64)
#pragma unroll
    for (int i = 0; i < 4; ++i) {
      int c = tid + 256 * i;
      int row = c >> 3, c8 = c & 7;
      u16x8 u;
      if (AF32) {
        const float* s = (const float*)Ag + (size_t)(mbase + row) * 1024 + k0 + c8 * 8;
        f32x4 f0 = *(const f32x4*)s;
        f32x4 f1 = *(const f32x4*)(s + 4);
#pragma unroll
        for (int j = 0; j < 4; ++j) u[j] = f2bf(f0[j]);
#pragma unroll
        for (int j = 0; j < 4; ++j) u[4 + j] = f2bf(f1[j]);
      } else {
        u = *(const u16x8*)((const unsigned short*)Ag + (size_t)(mbase + row) * 1024 + k0 + c8 * 8);
      }
      *reinterpret_cast<u16x8*>(&lA[row][c8 * 8]) = u;
    }
    // stage B tile (64 x 64) from W rows [nbase, nbase+64)
#pragma unroll
    for (int i = 0; i < 2; ++i) {
      int c = tid + 256 * i;
      int row = c >> 3, c8 = c & 7;
      const float* s = Wg + (size_t)(nbase + row) * 1024 + k0 + c8 * 8;
      f32x4 f0 = *(const f32x4*)s;
      f32x4 f1 = *(const f32x4*)(s + 4);
      u16x8 u;
#pragma unroll
      for (int j = 0; j < 4; ++j) u[j] = f2bf(f0[j]);
#pragma unroll
      for (int j = 0; j < 4; ++j) u[4 + j] = f2bf(f1[j]);
      *reinterpret_cast<u16x8*>(&lB[row][c8 * 8]) = u;
    }
    __syncthreads();
#pragma unroll
    for (int kk = 0; kk < 2; ++kk) {
      bf16x8 a[4], bb[2];
#pragma unroll
      for (int mi = 0; mi < 4; ++mi) a[mi] = ld8(&lA[wr * 64 + mi * 16 + lr][kk * 32 + lg * 8]);
#pragma unroll
      for (int ni = 0; ni < 2; ++ni) bb[ni] = ld8(&lB[wc * 32 + ni * 16 + lr][kk * 32 + lg * 8]);
#pragma unroll
      for (int mi = 0; mi < 4; ++mi)
#pragma unroll
        for (int ni = 0; ni < 2; ++ni)
          acc[mi][ni] = mfma16(a[mi], bb[ni], acc[mi][ni]);
    }
    __syncthreads();
  }

  // epilogue
#pragma unroll
  for (int ni = 0; ni < 2; ++ni) {
    const int n = nbase + wc * 32 + ni * 16 + lr;
    const float bv = bias[n];
#pragma unroll
    for (int mi = 0; mi < 4; ++mi) {
#pragma unroll
      for (int r = 0; r < 4; ++r) {
        const int m = mbase + wr * 64 + mi * 16 + lg * 4 + r;
        const float val = (acc[mi][ni][r] + bv) * scale;
        if (MODE == 0) {
          const int b = m >> 11, s = m & 2047, h = n >> 6, d = n & 63;
          ((unsigned short*)outg)[(((size_t)((b * 16 + h) * 2048 + s)) << 6) + d] = f2bf(val);
        } else if (MODE == 1) {
          const int b = m >> 11, s = m & 2047, h = n >> 6, d = n & 63;
          ((unsigned short*)outg)[(((size_t)((b * 16 + h) * 64 + d)) << 11) + s] = f2bf(val);
        } else {
          ((float*)outg)[(size_t)m * 1024 + n] = val;
        }
      }
    }
  }
}

// ---------------------------------------------------------------------------
// Flash attention. Grid: x = S/64 q-tiles (32), y = B*H (32). 256 thr = 4 waves.
// Wave w handles q rows [64*bx + 16w, +16). KBLK = 64 kv per step.
// Qh pre-scaled by 1/8, so scores = logits directly. mask additive -1e9 (fp32).
// ---------------------------------------------------------------------------
__global__ __launch_bounds__(256)
void attn_fwd(const unsigned short* __restrict__ Qh,
              const unsigned short* __restrict__ Kh,
              const unsigned short* __restrict__ Vt,
              const float* __restrict__ mask,
              unsigned short* __restrict__ Ao)
{
  __shared__ unsigned short lK[64][72];
  __shared__ unsigned short lV[64][72];
  __shared__ unsigned short lP[4][16][72];
  const int tid = threadIdx.x, lane = tid & 63, wid = tid >> 6;
  const int lr = lane & 15, lg = lane >> 4;
  const int bh = blockIdx.y;
  const int b = bh >> 4, h = bh & 15;
  const size_t head = (size_t)bh << 17;          // bh * S * 64
  const int qw = blockIdx.x * 64 + wid * 16;     // wave's first q row

  bf16x8 aq[2];
  {
    const u16x8* qp = (const u16x8*)(Qh + head + ((size_t)(qw + lr) << 6));
    aq[0] = __builtin_bit_cast(bf16x8, qp[lg]);
    aq[1] = __builtin_bit_cast(bf16x8, qp[4 + lg]);
  }

  const f32x4 zf = {0.f, 0.f, 0.f, 0.f};
  f32x4 o[4];
#pragma unroll
  for (int i = 0; i < 4; ++i) o[i] = zf;
  float m_run[4], l_run[4];
#pragma unroll
  for (int r = 0; r < 4; ++r) { m_run[r] = -3.0e38f; l_run[r] = 0.f; }

  const float* mptr = mask + ((size_t)b << 22) + (size_t)qw * 2048;

  for (int t = 0; t < 32; ++t) {
    const int kv0 = t * 64;
    // stage K (64x64) and Vt (64 d x 64 kv)
#pragma unroll
    for (int i = 0; i < 2; ++i) {
      int c = tid + 256 * i;
      int row = c >> 3, c8 = c & 7;
      *reinterpret_cast<u16x8*>(&lK[row][c8 * 8]) =
          *(const u16x8*)(Kh + head + ((size_t)(kv0 + row) << 6) + c8 * 8);
      *reinterpret_cast<u16x8*>(&lV[row][c8 * 8]) =
          *(const u16x8*)(Vt + head + ((size_t)row << 11) + kv0 + c8 * 8);
    }
    __syncthreads();

    // scores: S[16q][64kv] per wave, 4 frags along kv
    f32x4 sf[4];
#pragma unroll
    for (int f = 0; f < 4; ++f) {
      f32x4 z = zf;
      z = mfma16(aq[0], ld8(&lK[f * 16 + lr][lg * 8]), z);
      z = mfma16(aq[1], ld8(&lK[f * 16 + lr][32 + lg * 8]), z);
      sf[f] = z;
    }

    // mask + online softmax (per q-row r)
    float p[4][4];
#pragma unroll
    for (int r = 0; r < 4; ++r) {
      const float* mr = mptr + (size_t)(lg * 4 + r) * 2048 + kv0;
      float s0 = sf[0][r] - 1e9f * mr[lr];
      float s1 = sf[1][r] - 1e9f * mr[16 + lr];
      float s2 = sf[2][r] - 1e9f * mr[32 + lr];
      float s3 = sf[3][r] - 1e9f * mr[48 + lr];
      float mx = fmaxf(fmaxf(s0, s1), fmaxf(s2, s3));
      mx = fmaxf(mx, __shfl_xor(mx, 1));
      mx = fmaxf(mx, __shfl_xor(mx, 2));
      mx = fmaxf(mx, __shfl_xor(mx, 4));
      mx = fmaxf(mx, __shfl_xor(mx, 8));
      const float mn = fmaxf(m_run[r], mx);
      const float fac = __expf(m_run[r] - mn);
      m_run[r] = mn;
      float p0 = __expf(s0 - mn), p1 = __expf(s1 - mn);
      float p2 = __expf(s2 - mn), p3 = __expf(s3 - mn);
      p[0][r] = p0; p[1][r] = p1; p[2][r] = p2; p[3][r] = p3;
      float lt = p0 + p1 + p2 + p3;
      lt += __shfl_xor(lt, 1);
      lt += __shfl_xor(lt, 2);
      lt += __shfl_xor(lt, 4);
      lt += __shfl_xor(lt, 8);
      l_run[r] = l_run[r] * fac + lt;
#pragma unroll
      for (int fd = 0; fd < 4; ++fd) o[fd][r] *= fac;
    }

    // P -> LDS (bf16), re-shaped to A-fragment layout
#pragma unroll
    for (int f = 0; f < 4; ++f)
#pragma unroll
      for (int r = 0; r < 4; ++r)
        lP[wid][lg * 4 + r][f * 16 + lr] = f2bf(p[f][r]);

    // PV: O[16q][64d] += P[16q][64kv] * V[64kv][64d]  (V via Vt rows)
    bf16x8 pa0 = ld8(&lP[wid][lr][lg * 8]);
    bf16x8 pa1 = ld8(&lP[wid][lr][32 + lg * 8]);
#pragma unroll
    for (int fd = 0; fd < 4; ++fd) {
      o[fd] = mfma16(pa0, ld8(&lV[fd * 16 + lr][lg * 8]), o[fd]);
      o[fd] = mfma16(pa1, ld8(&lV[fd * 16 + lr][32 + lg * 8]), o[fd]);
    }
    __syncthreads();
  }

  // epilogue: normalize and write merged-head layout [B,S,H*64] bf16
  float inv[4];
#pragma unroll
  for (int r = 0; r < 4; ++r) inv[r] = 1.0f / l_run[r];
  unsigned short* op = Ao + (((size_t)(b * 2048 + blockIdx.x * 64 + wid * 16)) << 10) + h * 64;
#pragma unroll
  for (int fd = 0; fd < 4; ++fd)
#pragma unroll
    for (int r = 0; r < 4; ++r)
      op[((size_t)(lg * 4 + r) << 10) + fd * 16 + lr] = f2bf(o[fd][r] * inv[r]);
}

// ---------------------------------------------------------------------------
extern "C" void kernel_launch(void* const* d_in, const int* in_sizes, int n_in,
                              void* d_out, int out_size, void* d_ws, size_t ws_size,
                              hipStream_t stream) {
  const float* v    = (const float*)d_in[0];
  const float* k    = (const float*)d_in[1];
  const float* q    = (const float*)d_in[2];
  const float* mask = (const float*)d_in[3];
  const float* wq = (const float*)d_in[4];  const float* bq = (const float*)d_in[5];
  const float* wk = (const float*)d_in[6];  const float* bk = (const float*)d_in[7];
  const float* wv = (const float*)d_in[8];  const float* bv = (const float*)d_in[9];
  const float* wo = (const float*)d_in[10]; const float* bo = (const float*)d_in[11];

  unsigned short* ws = (unsigned short*)d_ws;
  unsigned short* Qh = ws;                       // 4194304 elems (8 MiB)
  unsigned short* Kh = ws + (size_t)4194304;
  unsigned short* Vt = ws + (size_t)2 * 4194304;
  unsigned short* Ao = ws + (size_t)3 * 4194304; // attention output, merged heads

  dim3 blk(256);
  dim3 gg(16, 32);   // N/64 x M/128

  gemm_proj<true, 0><<<gg, blk, 0, stream>>>(q, wq, bq, Qh, 0.125f);  // Q, pre-scaled
  gemm_proj<true, 0><<<gg, blk, 0, stream>>>(k, wk, bk, Kh, 1.0f);
  gemm_proj<true, 1><<<gg, blk, 0, stream>>>(v, wv, bv, Vt, 1.0f);

  attn_fwd<<<dim3(32, 32), blk, 0, stream>>>(Qh, Kh, Vt, mask, Ao);

  gemm_proj<false, 2><<<gg, blk, 0, stream>>>(Ao, wo, bo, d_out, 1.0f);
}

// Round 4
// 341.433 us; speedup vs baseline: 1.2482x; 1.2482x over previous
//
#include <hip/hip_runtime.h>

// MHA forward: D_MODEL=1024, H=16, DEPTH=64, B=2, S=2048, M=B*S=4096
// Round 4: pre-convert fp32->bf16, global_load_lds GEMM w/ XOR swizzle,
//          ballot-packed bitmask for the attention mask.

typedef float f32x4 __attribute__((ext_vector_type(4)));
typedef __bf16 bf16x8 __attribute__((ext_vector_type(8)));
typedef unsigned short u16x8 __attribute__((ext_vector_type(8)));

#define DEV static __device__ __forceinline__

DEV unsigned short f2bf(float x) {
  return __builtin_bit_cast(unsigned short, static_cast<__bf16>(x));
}
DEV bf16x8 ld8(const unsigned short* p) {
  return __builtin_bit_cast(bf16x8, *reinterpret_cast<const u16x8*>(p));
}
DEV f32x4 mfma16(bf16x8 a, bf16x8 b, f32x4 c) {
  return __builtin_amdgcn_mfma_f32_16x16x32_bf16(a, b, c, 0, 0, 0);
}
DEV void gl2lds16(const unsigned short* g, unsigned short* l) {
  __builtin_amdgcn_global_load_lds(
      (const __attribute__((address_space(1))) void*)g,
      (__attribute__((address_space(3))) void*)l, 16, 0, 0);
}

// ---------------------------------------------------------------------------
// fp32 -> bf16 converters (memory-bound pre-passes)
// ---------------------------------------------------------------------------
__global__ __launch_bounds__(256)
void cvt3(const float* __restrict__ a, const float* __restrict__ b,
          const float* __restrict__ c, unsigned short* __restrict__ oa,
          unsigned short* __restrict__ ob, unsigned short* __restrict__ oc)
{
  const float* in;
  unsigned short* out;
  if (blockIdx.y == 0) { in = a; out = oa; }
  else if (blockIdx.y == 1) { in = b; out = ob; }
  else { in = c; out = oc; }
  const size_t i = (size_t)blockIdx.x * 256 + threadIdx.x;  // * 8 elems
  const f32x4* p = (const f32x4*)(in + i * 8);
  f32x4 x = p[0], y = p[1];
  u16x8 u;
#pragma unroll
  for (int j = 0; j < 4; ++j) u[j] = f2bf(x[j]);
#pragma unroll
  for (int j = 0; j < 4; ++j) u[4 + j] = f2bf(y[j]);
  *(u16x8*)(out + i * 8) = u;
}

__global__ __launch_bounds__(256)
void cvt4(const float* __restrict__ a, const float* __restrict__ b,
          const float* __restrict__ c, const float* __restrict__ d,
          unsigned short* __restrict__ oa, unsigned short* __restrict__ ob,
          unsigned short* __restrict__ oc, unsigned short* __restrict__ od)
{
  const float* in;
  unsigned short* out;
  if (blockIdx.y == 0) { in = a; out = oa; }
  else if (blockIdx.y == 1) { in = b; out = ob; }
  else if (blockIdx.y == 2) { in = c; out = oc; }
  else { in = d; out = od; }
  const size_t i = (size_t)blockIdx.x * 256 + threadIdx.x;
  const f32x4* p = (const f32x4*)(in + i * 8);
  f32x4 x = p[0], y = p[1];
  u16x8 u;
#pragma unroll
  for (int j = 0; j < 4; ++j) u[j] = f2bf(x[j]);
#pragma unroll
  for (int j = 0; j < 4; ++j) u[4 + j] = f2bf(y[j]);
  *(u16x8*)(out + i * 8) = u;
}

// ---------------------------------------------------------------------------
// mask [B,1,S,S] fp32 (0/1) -> packed bits, word w covers elems [w*64, w*64+64)
// ---------------------------------------------------------------------------
__global__ __launch_bounds__(256)
void mask_bits(const float* __restrict__ m, unsigned long long* __restrict__ bits)
{
  const int l = threadIdx.x & 63;
  int w = blockIdx.x * 4 + (threadIdx.x >> 6);  // wave id, 8192 waves
#pragma unroll 1
  for (int i = 0; i < 16; ++i, w += 8192) {     // 131072 words total
    float v = m[(size_t)w * 64 + l];
    unsigned long long bl = __ballot(v != 0.0f);
    if (l == 0) bits[w] = bl;
  }
}

// ---------------------------------------------------------------------------
// bf16 GEMM: C[m][n] = sum_k A[m][k]*W[n][k] (+bias)*scale
// BM=128, BN=64, BK=64, 256 thr = 4 waves (2x2), wave tile 64x32.
// global_load_lds(16B) staging, linear LDS + XOR swizzle (both sides).
// MODE 0: bf16 [B,H,S,64]; MODE 1: bf16 [B,H,64,S]; MODE 2: fp32 [M,1024]
// ---------------------------------------------------------------------------
template<int MODE>
__global__ __launch_bounds__(256)
void gemm_bf16(const unsigned short* __restrict__ Ab,
               const unsigned short* __restrict__ Wb,
               const float* __restrict__ bias, void* __restrict__ outg,
               float scale)
{
  __shared__ unsigned short lA[128 * 64];
  __shared__ unsigned short lB[64 * 64];
  const int tid = threadIdx.x, lane = tid & 63, wid = tid >> 6;
  const int lr = lane & 15, lg = lane >> 4;
  const int wr = wid >> 1, wc = wid & 1;
  const int mbase = blockIdx.y * 128, nbase = blockIdx.x * 64;
  const int rsub = lane >> 3;                      // 0..7 row within chunk
  const int colsw = ((lane & 7) ^ rsub) * 8;       // pre-swizzled global col (elems)

  const f32x4 zf = {0.f, 0.f, 0.f, 0.f};
  f32x4 acc[4][2];
#pragma unroll
  for (int i = 0; i < 4; ++i)
#pragma unroll
    for (int j = 0; j < 2; ++j) acc[i][j] = zf;

  for (int kt = 0; kt < 16; ++kt) {
    const int k0 = kt * 64;
    // A tile: 128x64 bf16 = 16 chunks of 1 KiB (8 rows each)
#pragma unroll
    for (int i = 0; i < 4; ++i) {
      const int c = wid + 4 * i;
      const int row = c * 8 + rsub;
      gl2lds16(Ab + (size_t)(mbase + row) * 1024 + k0 + colsw, &lA[c * 512]);
    }
    // B tile: 64x64 = 8 chunks
#pragma unroll
    for (int i = 0; i < 2; ++i) {
      const int c = wid + 4 * i;
      const int row = c * 8 + rsub;
      gl2lds16(Wb + (size_t)(nbase + row) * 1024 + k0 + colsw, &lB[c * 512]);
    }
    __syncthreads();   // compiler drains vmcnt(0) before barrier

#pragma unroll
    for (int kk = 0; kk < 2; ++kk) {
      const int sw = (((kk * 4 + lg) ^ (lr & 7)) * 8);  // swizzled read col
      bf16x8 a[4], bb[2];
#pragma unroll
      for (int mi = 0; mi < 4; ++mi)
        a[mi] = ld8(&lA[(wr * 64 + mi * 16 + lr) * 64 + sw]);
#pragma unroll
      for (int ni = 0; ni < 2; ++ni)
        bb[ni] = ld8(&lB[(wc * 32 + ni * 16 + lr) * 64 + sw]);
#pragma unroll
      for (int mi = 0; mi < 4; ++mi)
#pragma unroll
        for (int ni = 0; ni < 2; ++ni)
          acc[mi][ni] = mfma16(a[mi], bb[ni], acc[mi][ni]);
    }
    __syncthreads();
  }

  // epilogue: C/D layout col=lane&15 (n), row=(lane>>4)*4+r (m)
#pragma unroll
  for (int ni = 0; ni < 2; ++ni) {
    const int n = nbase + wc * 32 + ni * 16 + lr;
    const float bv = bias[n];
#pragma unroll
    for (int mi = 0; mi < 4; ++mi) {
#pragma unroll
      for (int r = 0; r < 4; ++r) {
        const int m = mbase + wr * 64 + mi * 16 + lg * 4 + r;
        const float val = (acc[mi][ni][r] + bv) * scale;
        if (MODE == 0) {
          const int b = m >> 11, s = m & 2047, h = n >> 6, d = n & 63;
          ((unsigned short*)outg)[(((size_t)((b * 16 + h) * 2048 + s)) << 6) + d] = f2bf(val);
        } else if (MODE == 1) {
          const int b = m >> 11, s = m & 2047, h = n >> 6, d = n & 63;
          ((unsigned short*)outg)[(((size_t)((b * 16 + h) * 64 + d)) << 11) + s] = f2bf(val);
        } else {
          ((float*)outg)[(size_t)m * 1024 + n] = val;
        }
      }
    }
  }
}

// ---------------------------------------------------------------------------
// Flash attention. Grid: x = S/64 q-tiles (32), y = B*H (32). 256 thr = 4 waves.
// Mask comes in as packed bits: word (b*2048+qr)*32 + t covers kv [t*64,+64).
// ---------------------------------------------------------------------------
__global__ __launch_bounds__(256)
void attn_fwd(const unsigned short* __restrict__ Qh,
              const unsigned short* __restrict__ Kh,
              const unsigned short* __restrict__ Vt,
              const unsigned long long* __restrict__ bits,
              unsigned short* __restrict__ Ao)
{
  __shared__ unsigned short lK[64][72];
  __shared__ unsigned short lV[64][72];
  __shared__ unsigned short lP[4][16][72];
  const int tid = threadIdx.x, lane = tid & 63, wid = tid >> 6;
  const int lr = lane & 15, lg = lane >> 4;
  const int bh = blockIdx.y;
  const int b = bh >> 4, h = bh & 15;
  const size_t head = (size_t)bh << 17;
  const int qw = blockIdx.x * 64 + wid * 16;

  bf16x8 aq[2];
  {
    const u16x8* qp = (const u16x8*)(Qh + head + ((size_t)(qw + lr) << 6));
    aq[0] = __builtin_bit_cast(bf16x8, qp[lg]);
    aq[1] = __builtin_bit_cast(bf16x8, qp[4 + lg]);
  }

  const f32x4 zf = {0.f, 0.f, 0.f, 0.f};
  f32x4 o[4];
#pragma unroll
  for (int i = 0; i < 4; ++i) o[i] = zf;
  float m_run[4], l_run[4];
#pragma unroll
  for (int r = 0; r < 4; ++r) { m_run[r] = -3.0e38f; l_run[r] = 0.f; }

  const unsigned long long* bptr = bits + ((size_t)b * 2048 + qw) * 32;

  for (int t = 0; t < 32; ++t) {
    const int kv0 = t * 64;
#pragma unroll
    for (int i = 0; i < 2; ++i) {
      int c = tid + 256 * i;
      int row = c >> 3, c8 = c & 7;
      *reinterpret_cast<u16x8*>(&lK[row][c8 * 8]) =
          *(const u16x8*)(Kh + head + ((size_t)(kv0 + row) << 6) + c8 * 8);
      *reinterpret_cast<u16x8*>(&lV[row][c8 * 8]) =
          *(const u16x8*)(Vt + head + ((size_t)row << 11) + kv0 + c8 * 8);
    }
    __syncthreads();

    f32x4 sf[4];
#pragma unroll
    for (int f = 0; f < 4; ++f) {
      f32x4 z = zf;
      z = mfma16(aq[0], ld8(&lK[f * 16 + lr][lg * 8]), z);
      z = mfma16(aq[1], ld8(&lK[f * 16 + lr][32 + lg * 8]), z);
      sf[f] = z;
    }

    float p[4][4];
#pragma unroll
    for (int r = 0; r < 4; ++r) {
      const unsigned long long mb = bptr[(size_t)(lg * 4 + r) * 32 + t];
      float s0 = sf[0][r] - (((mb >> (lr)) & 1) ? 1e9f : 0.f);
      float s1 = sf[1][r] - (((mb >> (16 + lr)) & 1) ? 1e9f : 0.f);
      float s2 = sf[2][r] - (((mb >> (32 + lr)) & 1) ? 1e9f : 0.f);
      float s3 = sf[3][r] - (((mb >> (48 + lr)) & 1) ? 1e9f : 0.f);
      float mx = fmaxf(fmaxf(s0, s1), fmaxf(s2, s3));
      mx = fmaxf(mx, __shfl_xor(mx, 1));
      mx = fmaxf(mx, __shfl_xor(mx, 2));
      mx = fmaxf(mx, __shfl_xor(mx, 4));
      mx = fmaxf(mx, __shfl_xor(mx, 8));
      const float mn = fmaxf(m_run[r], mx);
      const float fac = __expf(m_run[r] - mn);
      m_run[r] = mn;
      float p0 = __expf(s0 - mn), p1 = __expf(s1 - mn);
      float p2 = __expf(s2 - mn), p3 = __expf(s3 - mn);
      p[0][r] = p0; p[1][r] = p1; p[2][r] = p2; p[3][r] = p3;
      float lt = p0 + p1 + p2 + p3;
      lt += __shfl_xor(lt, 1);
      lt += __shfl_xor(lt, 2);
      lt += __shfl_xor(lt, 4);
      lt += __shfl_xor(lt, 8);
      l_run[r] = l_run[r] * fac + lt;
#pragma unroll
      for (int fd = 0; fd < 4; ++fd) o[fd][r] *= fac;
    }

#pragma unroll
    for (int f = 0; f < 4; ++f)
#pragma unroll
      for (int r = 0; r < 4; ++r)
        lP[wid][lg * 4 + r][f * 16 + lr] = f2bf(p[f][r]);

    bf16x8 pa0 = ld8(&lP[wid][lr][lg * 8]);
    bf16x8 pa1 = ld8(&lP[wid][lr][32 + lg * 8]);
#pragma unroll
    for (int fd = 0; fd < 4; ++fd) {
      o[fd] = mfma16(pa0, ld8(&lV[fd * 16 + lr][lg * 8]), o[fd]);
      o[fd] = mfma16(pa1, ld8(&lV[fd * 16 + lr][32 + lg * 8]), o[fd]);
    }
    __syncthreads();
  }

  float inv[4];
#pragma unroll
  for (int r = 0; r < 4; ++r) inv[r] = 1.0f / l_run[r];
  unsigned short* op = Ao + (((size_t)(b * 2048 + blockIdx.x * 64 + wid * 16)) << 10) + h * 64;
#pragma unroll
  for (int fd = 0; fd < 4; ++fd)
#pragma unroll
    for (int r = 0; r < 4; ++r)
      op[((size_t)(lg * 4 + r) << 10) + fd * 16 + lr] = f2bf(o[fd][r] * inv[r]);
}

// ---------------------------------------------------------------------------
extern "C" void kernel_launch(void* const* d_in, const int* in_sizes, int n_in,
                              void* d_out, int out_size, void* d_ws, size_t ws_size,
                              hipStream_t stream) {
  const float* v    = (const float*)d_in[0];
  const float* k    = (const float*)d_in[1];
  const float* q    = (const float*)d_in[2];
  const float* mask = (const float*)d_in[3];
  const float* wq = (const float*)d_in[4];  const float* bq = (const float*)d_in[5];
  const float* wk = (const float*)d_in[6];  const float* bk = (const float*)d_in[7];
  const float* wv = (const float*)d_in[8];  const float* bv = (const float*)d_in[9];
  const float* wo = (const float*)d_in[10]; const float* bo = (const float*)d_in[11];

  unsigned short* ws = (unsigned short*)d_ws;
  const size_t T = 4194304;   // 4096*1024
  unsigned short* Qh  = ws;
  unsigned short* Kh  = ws + T;
  unsigned short* Vt  = ws + 2 * T;
  unsigned short* Ao  = ws + 3 * T;
  unsigned short* Qb  = ws + 4 * T;
  unsigned short* Kb  = ws + 5 * T;
  unsigned short* Vb  = ws + 6 * T;
  unsigned short* Wqb = ws + 7 * T;
  unsigned short* Wkb = Wqb + 1048576;
  unsigned short* Wvb = Wkb + 1048576;
  unsigned short* Wob = Wvb + 1048576;
  unsigned long long* bits = (unsigned long long*)(ws + 8 * T);  // 1 MiB

  dim3 blk(256);
  cvt3<<<dim3(2048, 3), blk, 0, stream>>>(q, k, v, Qb, Kb, Vb);
  cvt4<<<dim3(512, 4), blk, 0, stream>>>(wq, wk, wv, wo, Wqb, Wkb, Wvb, Wob);
  mask_bits<<<dim3(2048), blk, 0, stream>>>(mask, bits);

  dim3 gg(16, 32);   // N/64 x M/128
  gemm_bf16<0><<<gg, blk, 0, stream>>>(Qb, Wqb, bq, Qh, 0.125f);
  gemm_bf16<0><<<gg, blk, 0, stream>>>(Kb, Wkb, bk, Kh, 1.0f);
  gemm_bf16<1><<<gg, blk, 0, stream>>>(Vb, Wvb, bv, Vt, 1.0f);

  attn_fwd<<<dim3(32, 32), blk, 0, stream>>>(Qh, Kh, Vt, bits, Ao);

  gemm_bf16<2><<<gg, blk, 0, stream>>>(Ao, Wob, bo, d_out, 1.0f);
}

// Round 8
// 302.029 us; speedup vs baseline: 1.4111x; 1.1305x over previous
//
#include <hip/hip_runtime.h>

// MHA forward: D_MODEL=1024, H=16, DEPTH=64, B=2, S=2048, M=B*S=4096
// Round 7 (resubmit; 3rd infra failure): attn rewrite — swapped QK^T
// (lane-local softmax rows), XOR-swizzled K/V/P LDS with global_load_lds
// staging, b64 P writes. Q+K GEMM fused.

typedef float f32x4 __attribute__((ext_vector_type(4)));
typedef __bf16 bf16x8 __attribute__((ext_vector_type(8)));
typedef unsigned short u16x8 __attribute__((ext_vector_type(8)));
typedef unsigned short u16x4 __attribute__((ext_vector_type(4)));

#define DEV static __device__ __forceinline__

DEV unsigned short f2bf(float x) {
  return __builtin_bit_cast(unsigned short, static_cast<__bf16>(x));
}
DEV bf16x8 ld8(const unsigned short* p) {
  return __builtin_bit_cast(bf16x8, *reinterpret_cast<const u16x8*>(p));
}
DEV f32x4 mfma16(bf16x8 a, bf16x8 b, f32x4 c) {
  return __builtin_amdgcn_mfma_f32_16x16x32_bf16(a, b, c, 0, 0, 0);
}
DEV void gl2lds16(const unsigned short* g, unsigned short* l) {
  __builtin_amdgcn_global_load_lds(
      (const __attribute__((address_space(1))) void*)g,
      (__attribute__((address_space(3))) void*)l, 16, 0, 0);
}

// ---------------------------------------------------------------------------
// fp32 -> bf16 converters (memory-bound pre-passes)
// ---------------------------------------------------------------------------
__global__ __launch_bounds__(256)
void cvt3(const float* __restrict__ a, const float* __restrict__ b,
          const float* __restrict__ c, unsigned short* __restrict__ oa,
          unsigned short* __restrict__ ob, unsigned short* __restrict__ oc)
{
  const float* in;
  unsigned short* out;
  if (blockIdx.y == 0) { in = a; out = oa; }
  else if (blockIdx.y == 1) { in = b; out = ob; }
  else { in = c; out = oc; }
  const size_t i = (size_t)blockIdx.x * 256 + threadIdx.x;  // * 8 elems
  const f32x4* p = (const f32x4*)(in + i * 8);
  f32x4 x = p[0], y = p[1];
  u16x8 u;
#pragma unroll
  for (int j = 0; j < 4; ++j) u[j] = f2bf(x[j]);
#pragma unroll
  for (int j = 0; j < 4; ++j) u[4 + j] = f2bf(y[j]);
  *(u16x8*)(out + i * 8) = u;
}

__global__ __launch_bounds__(256)
void cvt4(const float* __restrict__ a, const float* __restrict__ b,
          const float* __restrict__ c, const float* __restrict__ d,
          unsigned short* __restrict__ oa, unsigned short* __restrict__ ob,
          unsigned short* __restrict__ oc, unsigned short* __restrict__ od)
{
  const float* in;
  unsigned short* out;
  if (blockIdx.y == 0) { in = a; out = oa; }
  else if (blockIdx.y == 1) { in = b; out = ob; }
  else if (blockIdx.y == 2) { in = c; out = oc; }
  else { in = d; out = od; }
  const size_t i = (size_t)blockIdx.x * 256 + threadIdx.x;
  const f32x4* p = (const f32x4*)(in + i * 8);
  f32x4 x = p[0], y = p[1];
  u16x8 u;
#pragma unroll
  for (int j = 0; j < 4; ++j) u[j] = f2bf(x[j]);
#pragma unroll
  for (int j = 0; j < 4; ++j) u[4 + j] = f2bf(y[j]);
  *(u16x8*)(out + i * 8) = u;
}

// ---------------------------------------------------------------------------
// mask [B,1,S,S] fp32 (0/1) -> packed bits, word w covers elems [w*64, w*64+64)
// ---------------------------------------------------------------------------
__global__ __launch_bounds__(256)
void mask_bits(const float* __restrict__ m, unsigned long long* __restrict__ bits)
{
  const int l = threadIdx.x & 63;
  int w = blockIdx.x * 4 + (threadIdx.x >> 6);
#pragma unroll 1
  for (int i = 0; i < 16; ++i, w += 8192) {
    float v = m[(size_t)w * 64 + l];
    unsigned long long bl = __ballot(v != 0.0f);
    if (l == 0) bits[w] = bl;
  }
}

// ---------------------------------------------------------------------------
// bf16 GEMM: C[m][n] = sum_k A[m][k]*W[n][k] (+bias)*scale
// BM=128, BN=64, BK=64, 256 thr = 4 waves (2x2), wave tile 64x32.
// global_load_lds(16B), linear LDS + XOR swizzle. blockIdx.z picks set 0/1.
// MODE 0: bf16 [B,H,S,64]; MODE 1: bf16 [B,H,64,S]; MODE 2: fp32 [M,1024]
// ---------------------------------------------------------------------------
template<int MODE>
__global__ __launch_bounds__(256)
void gemm_bf16(const unsigned short* __restrict__ A0,
               const unsigned short* __restrict__ W0,
               const float* __restrict__ b0, void* __restrict__ o0, float sc0,
               const unsigned short* __restrict__ A1,
               const unsigned short* __restrict__ W1,
               const float* __restrict__ b1, void* __restrict__ o1, float sc1)
{
  const unsigned short* Ab = blockIdx.z ? A1 : A0;
  const unsigned short* Wb = blockIdx.z ? W1 : W0;
  const float* bias = blockIdx.z ? b1 : b0;
  void* outg = blockIdx.z ? o1 : o0;
  const float scale = blockIdx.z ? sc1 : sc0;

  __shared__ unsigned short lA[128 * 64];
  __shared__ unsigned short lB[64 * 64];
  const int tid = threadIdx.x, lane = tid & 63, wid = tid >> 6;
  const int lr = lane & 15, lg = lane >> 4;
  const int wr = wid >> 1, wc = wid & 1;
  const int mbase = blockIdx.y * 128, nbase = blockIdx.x * 64;
  const int rsub = lane >> 3;
  const int colsw = ((lane & 7) ^ rsub) * 8;

  const f32x4 zf = {0.f, 0.f, 0.f, 0.f};
  f32x4 acc[4][2];
#pragma unroll
  for (int i = 0; i < 4; ++i)
#pragma unroll
    for (int j = 0; j < 2; ++j) acc[i][j] = zf;

  for (int kt = 0; kt < 16; ++kt) {
    const int k0 = kt * 64;
#pragma unroll
    for (int i = 0; i < 4; ++i) {
      const int c = wid + 4 * i;
      const int row = c * 8 + rsub;
      gl2lds16(Ab + (size_t)(mbase + row) * 1024 + k0 + colsw, &lA[c * 512]);
    }
#pragma unroll
    for (int i = 0; i < 2; ++i) {
      const int c = wid + 4 * i;
      const int row = c * 8 + rsub;
      gl2lds16(Wb + (size_t)(nbase + row) * 1024 + k0 + colsw, &lB[c * 512]);
    }
    __syncthreads();

#pragma unroll
    for (int kk = 0; kk < 2; ++kk) {
      const int sw = (((kk * 4 + lg) ^ (lr & 7)) * 8);
      bf16x8 a[4], bb[2];
#pragma unroll
      for (int mi = 0; mi < 4; ++mi)
        a[mi] = ld8(&lA[(wr * 64 + mi * 16 + lr) * 64 + sw]);
#pragma unroll
      for (int ni = 0; ni < 2; ++ni)
        bb[ni] = ld8(&lB[(wc * 32 + ni * 16 + lr) * 64 + sw]);
#pragma unroll
      for (int mi = 0; mi < 4; ++mi)
#pragma unroll
        for (int ni = 0; ni < 2; ++ni)
          acc[mi][ni] = mfma16(a[mi], bb[ni], acc[mi][ni]);
    }
    __syncthreads();
  }

#pragma unroll
  for (int ni = 0; ni < 2; ++ni) {
    const int n = nbase + wc * 32 + ni * 16 + lr;
    const float bv = bias[n];
#pragma unroll
    for (int mi = 0; mi < 4; ++mi) {
#pragma unroll
      for (int r = 0; r < 4; ++r) {
        const int m = mbase + wr * 64 + mi * 16 + lg * 4 + r;
        const float val = (acc[mi][ni][r] + bv) * scale;
        if (MODE == 0) {
          const int b = m >> 11, s = m & 2047, h = n >> 6, d = n & 63;
          ((unsigned short*)outg)[(((size_t)((b * 16 + h) * 2048 + s)) << 6) + d] = f2bf(val);
        } else if (MODE == 1) {
          const int b = m >> 11, s = m & 2047, h = n >> 6, d = n & 63;
          ((unsigned short*)outg)[(((size_t)((b * 16 + h) * 64 + d)) << 11) + s] = f2bf(val);
        } else {
          ((float*)outg)[(size_t)m * 1024 + n] = val;
        }
      }
    }
  }
}

// ---------------------------------------------------------------------------
// Flash attention, swapped QK^T. Grid: x = S/64 (32), y = B*H (32). 4 waves.
// Wave w: q rows [64*bx + 16w, +16). KBLK=64.
// S^T = mfma(K, Q): lane (lr,lg) holds S[kv=f*16+lg*4+r][q=lr] -> row softmax
// is in-lane over 16 vals + shfl_xor(16,32). P stored [q][kv] via b64 writes.
// All LDS tiles XOR-swizzled in 16B granules: granule ^= (row&7).
// ---------------------------------------------------------------------------
__global__ __launch_bounds__(256)
void attn_fwd(const unsigned short* __restrict__ Qh,
              const unsigned short* __restrict__ Kh,
              const unsigned short* __restrict__ Vt,
              const unsigned long long* __restrict__ bits,
              unsigned short* __restrict__ Ao)
{
  __shared__ unsigned short lK[64 * 64];
  __shared__ unsigned short lV[64 * 64];
  __shared__ unsigned short lP[4 * 1024];   // per wave [16 q][64 kv]
  const int tid = threadIdx.x, lane = tid & 63, wid = tid >> 6;
  const int lr = lane & 15, lg = lane >> 4;
  const int a7 = lr & 7;
  const int rsub = lane >> 3;
  const int colsw = ((lane & 7) ^ rsub) * 8;
  const int bh = blockIdx.y;
  const int b = bh >> 4, h = bh & 15;
  const size_t head = (size_t)bh << 17;
  const int qw = blockIdx.x * 64 + wid * 16;

  bf16x8 aq[2];
  {
    const u16x8* qp = (const u16x8*)(Qh + head + ((size_t)(qw + lr) << 6));
    aq[0] = __builtin_bit_cast(bf16x8, qp[lg]);
    aq[1] = __builtin_bit_cast(bf16x8, qp[4 + lg]);
  }

  const f32x4 zf = {0.f, 0.f, 0.f, 0.f};
  f32x4 o[4];
#pragma unroll
  for (int i = 0; i < 4; ++i) o[i] = zf;
  float m_run = -3.0e38f, l_run = 0.f;   // per-lane scalars for q = qw + lr

  const unsigned long long* bptr = bits + ((size_t)b * 2048 + qw) * 32;
  const int g0 = (lg ^ a7) * 8;          // swizzled granule, half 0
  const int g1 = ((4 + lg) ^ a7) * 8;    // half 1

  for (int t = 0; t < 32; ++t) {
    const int kv0 = t * 64;
    // stage K (64 kv x 64 d) and V (64 d x 64 kv), swizzled source cols
#pragma unroll
    for (int i = 0; i < 2; ++i) {
      const int c = wid + 4 * i;
      gl2lds16(Kh + head + (size_t)(kv0 + c * 8 + rsub) * 64 + colsw, &lK[c * 512]);
      gl2lds16(Vt + head + (size_t)(c * 8 + rsub) * 2048 + kv0 + colsw, &lV[c * 512]);
    }
    __syncthreads();

    // S^T frags: sf[f][r] = S[kv = f*16+lg*4+r][q = lr]
    f32x4 sf[4];
#pragma unroll
    for (int f = 0; f < 4; ++f) {
      const int row = (f * 16 + lr) * 64;
      f32x4 z = mfma16(ld8(&lK[row + g0]), aq[0], zf);
      sf[f] = mfma16(ld8(&lK[row + g1]), aq[1], z);
    }

    // mask (bit -> -1e9)
    const unsigned long long mq = bptr[lr * 32 + t] >> (lg * 4);
#pragma unroll
    for (int f = 0; f < 4; ++f) {
      const unsigned nib = (unsigned)(mq >> (f * 16)) & 0xFu;
#pragma unroll
      for (int r = 0; r < 4; ++r)
        sf[f][r] -= ((nib >> r) & 1u) ? 1e9f : 0.0f;
    }

    // in-lane row max + cross-lg reduce
    f32x4 mm;
#pragma unroll
    for (int r = 0; r < 4; ++r)
      mm[r] = fmaxf(fmaxf(sf[0][r], sf[1][r]), fmaxf(sf[2][r], sf[3][r]));
    float mx = fmaxf(fmaxf(mm[0], mm[1]), fmaxf(mm[2], mm[3]));
    mx = fmaxf(mx, __shfl_xor(mx, 16));
    mx = fmaxf(mx, __shfl_xor(mx, 32));

    const float mn = fmaxf(m_run, mx);
    const float fac = __expf(m_run - mn);
    m_run = mn;

    // p = exp(s - mn), accumulate sum, pack bf16
    f32x4 psum = zf;
    u16x4 pw[4];
#pragma unroll
    for (int f = 0; f < 4; ++f) {
#pragma unroll
      for (int r = 0; r < 4; ++r) {
        const float pv = __expf(sf[f][r] - mn);
        psum[r] += pv;
        pw[f][r] = f2bf(pv);
      }
    }
    float lt = (psum[0] + psum[1]) + (psum[2] + psum[3]);
    lt += __shfl_xor(lt, 16);
    lt += __shfl_xor(lt, 32);
    l_run = l_run * fac + lt;

    // P -> LDS [q][kv], swizzled b64 writes (4 r-values contiguous in kv)
#pragma unroll
    for (int f = 0; f < 4; ++f) {
      const int g = ((f * 2 + (lg >> 1)) ^ a7) * 8 + (lg & 1) * 4;
      *(u16x4*)&lP[wid * 1024 + lr * 64 + g] = pw[f];
    }

    // rescale O by fac (broadcast from q-owner lanes)
#pragma unroll
    for (int r = 0; r < 4; ++r) {
      const float fr = __shfl(fac, lg * 4 + r);
#pragma unroll
      for (int fd = 0; fd < 4; ++fd) o[fd][r] *= fr;
    }

    // PV: O[q][d] += P[q][kv] * V[kv][d]
    bf16x8 pa0 = ld8(&lP[wid * 1024 + lr * 64 + g0]);
    bf16x8 pa1 = ld8(&lP[wid * 1024 + lr * 64 + g1]);
#pragma unroll
    for (int fd = 0; fd < 4; ++fd) {
      const int vrow = (fd * 16 + lr) * 64;
      o[fd] = mfma16(pa0, ld8(&lV[vrow + g0]), o[fd]);
      o[fd] = mfma16(pa1, ld8(&lV[vrow + g1]), o[fd]);
    }
    __syncthreads();
  }

  // epilogue: normalize, write merged-head [B,S,1024] bf16
  const float linv = 1.0f / l_run;
  float invr[4];
#pragma unroll
  for (int r = 0; r < 4; ++r) invr[r] = __shfl(linv, lg * 4 + r);
  unsigned short* op = Ao + (((size_t)(b * 2048 + blockIdx.x * 64 + wid * 16)) << 10) + h * 64;
#pragma unroll
  for (int fd = 0; fd < 4; ++fd)
#pragma unroll
    for (int r = 0; r < 4; ++r)
      op[((size_t)(lg * 4 + r) << 10) + fd * 16 + lr] = f2bf(o[fd][r] * invr[r]);
}

// ---------------------------------------------------------------------------
extern "C" void kernel_launch(void* const* d_in, const int* in_sizes, int n_in,
                              void* d_out, int out_size, void* d_ws, size_t ws_size,
                              hipStream_t stream) {
  const float* v    = (const float*)d_in[0];
  const float* k    = (const float*)d_in[1];
  const float* q    = (const float*)d_in[2];
  const float* mask = (const float*)d_in[3];
  const float* wq = (const float*)d_in[4];  const float* bq = (const float*)d_in[5];
  const float* wk = (const float*)d_in[6];  const float* bk = (const float*)d_in[7];
  const float* wv = (const float*)d_in[8];  const float* bv = (const float*)d_in[9];
  const float* wo = (const float*)d_in[10]; const float* bo = (const float*)d_in[11];

  unsigned short* ws = (unsigned short*)d_ws;
  const size_t T = 4194304;   // 4096*1024
  unsigned short* Qh  = ws;
  unsigned short* Kh  = ws + T;
  unsigned short* Vt  = ws + 2 * T;
  unsigned short* Ao  = ws + 3 * T;
  unsigned short* Qb  = ws + 4 * T;
  unsigned short* Kb  = ws + 5 * T;
  unsigned short* Vb  = ws + 6 * T;
  unsigned short* Wqb = ws + 7 * T;
  unsigned short* Wkb = Wqb + 1048576;
  unsigned short* Wvb = Wkb + 1048576;
  unsigned short* Wob = Wvb + 1048576;
  unsigned long long* bits = (unsigned long long*)(ws + 8 * T);

  dim3 blk(256);
  cvt3<<<dim3(2048, 3), blk, 0, stream>>>(q, k, v, Qb, Kb, Vb);
  cvt4<<<dim3(512, 4), blk, 0, stream>>>(wq, wk, wv, wo, Wqb, Wkb, Wvb, Wob);
  mask_bits<<<dim3(2048), blk, 0, stream>>>(mask, bits);

  // Q and K projections fused via blockIdx.z
  gemm_bf16<0><<<dim3(16, 32, 2), blk, 0, stream>>>(
      Qb, Wqb, bq, Qh, 0.125f, Kb, Wkb, bk, Kh, 1.0f);
  gemm_bf16<1><<<dim3(16, 32, 1), blk, 0, stream>>>(
      Vb, Wvb, bv, Vt, 1.0f, Vb, Wvb, bv, Vt, 1.0f);

  attn_fwd<<<dim3(32, 32), blk, 0, stream>>>(Qh, Kh, Vt, bits, Ao);

  gemm_bf16<2><<<dim3(16, 32, 1), blk, 0, stream>>>(
      Ao, Wob, bo, d_out, 1.0f, Ao, Wob, bo, d_out, 1.0f);
}